// Round 1
// 2059.491 us; speedup vs baseline: 1.7468x; 1.7468x over previous
//
#include <hip/hip_runtime.h>
#include <cstdint>
#include <cstddef>

// ---------- types / helpers ----------
typedef short short8 __attribute__((ext_vector_type(8)));
typedef float f32x4 __attribute__((ext_vector_type(4)));

__device__ __forceinline__ float b2f(unsigned short u) {
    union { unsigned int i; float fl; } c; c.i = ((unsigned int)u) << 16; return c.fl;
}
__device__ __forceinline__ unsigned short f2b(float v) {
    union { float fl; unsigned int i; } c; c.fl = v;
    unsigned int x = c.i;
    x += 0x7fffu + ((x >> 16) & 1u);   // round-to-nearest-even
    return (unsigned short)(x >> 16);
}

// async global->LDS, 16B per lane. LDS dest must be linear in lane order.
#define GLD16(g, l) __builtin_amdgcn_global_load_lds( \
    (__attribute__((address_space(1))) void*)(g), \
    (__attribute__((address_space(3))) void*)(l), 16, 0, 0)

// ---------- runtime dtype detection ----------
// flags[0]=1 if float tensors are fp32 (else bf16); flags[1]=1 if x is int64 (else int32).
__global__ __launch_bounds__(256) void detect_kernel(const void* __restrict__ xp,
    const void* __restrict__ tokp, int* __restrict__ flags)
{
    __shared__ int sh[2];
    if (threadIdx.x == 0) { sh[0] = 0; sh[1] = 1; }
    __syncthreads();
    const unsigned short* tu = (const unsigned short*)tokp;
    int lf = 0;
    for (int i = threadIdx.x; i < 2048; i += 256) {
        float v = b2f(tu[i]);
        if (!(fabsf(v) < 1e6f)) lf = 1;    // catches huge and NaN
    }
    if (lf) sh[0] = 1;
    const int* xi = (const int*)xp;
    int nz = 0;
    for (int i = 2 * threadIdx.x + 1; i < 2048; i += 512) {
        if (xi[i] != 0) nz = 1;
    }
    if (nz) sh[1] = 0;
    __syncthreads();
    if (threadIdx.x == 0) { flags[0] = sh[0]; flags[1] = sh[1]; }
}

// ---------- canonicalize small tensors (biases / LN params) to bf16 ----------
struct P13 { const void* p[13]; };
__device__ __constant__ int cvt_n[13]    = {3072,3072,3072,3072,3072,3072,3072,3072,12288,3072,1024,1024,32000};
__device__ __constant__ int cvt_off[13]  = {0,1024,2048,9216,12288,15360,18432,21504,24576,36864,39936,40960,41984};
__device__ __constant__ int cvt_mode[13] = {1,1,1,0,0,0,0,0,0,0,0,0,0};

__global__ __launch_bounds__(256) void cvt_kernel(P13 ps, unsigned short* __restrict__ sb,
                                                  const int* __restrict__ flags)
{
    const int t = blockIdx.y;
    const int i = blockIdx.x * 256 + threadIdx.x;
    if (i >= cvt_n[t]) return;
    float v = flags[0] ? ((const float*)ps.p[t])[i] : b2f(((const unsigned short*)ps.p[t])[i]);
    int dst = cvt_off[t] + (cvt_mode[t] ? ((i >> 10) * 3072 + (i & 1023)) : i);
    sb[dst] = f2b(v);
}

// ---------- embedding: h = tok_emb[x] + pos_emb (fp32 out) ----------
__global__ __launch_bounds__(256) void embed_kernel(const void* __restrict__ xp,
    const void* __restrict__ tokp, const void* __restrict__ posp,
    float* __restrict__ h, const int* __restrict__ flags)
{
    const int f32 = flags[0], x64 = flags[1];
    const int row = blockIdx.x;        // 0..2047
    const int s = row & 1023;
    const long long t = x64 ? ((const long long*)xp)[row] : (long long)((const int*)xp)[row];
    const int d = threadIdx.x * 4;
    float4 o;
    if (f32) {
        float4 tv = *(const float4*)((const float*)tokp + t * 1024 + d);
        float4 pv = *(const float4*)((const float*)posp + (size_t)s * 1024 + d);
        o.x = tv.x + pv.x; o.y = tv.y + pv.y; o.z = tv.z + pv.z; o.w = tv.w + pv.w;
    } else {
        ushort4 tv = *(const ushort4*)((const unsigned short*)tokp + t * 1024 + d);
        ushort4 pv = *(const ushort4*)((const unsigned short*)posp + (size_t)s * 1024 + d);
        o.x = b2f(tv.x) + b2f(pv.x);
        o.y = b2f(tv.y) + b2f(pv.y);
        o.z = b2f(tv.z) + b2f(pv.z);
        o.w = b2f(tv.w) + b2f(pv.w);
    }
    *(float4*)(h + (size_t)row * 1024 + d) = o;
}

// ---------- layernorm (fp32 in, bf16 out); g,b canonical bf16 ----------
__device__ __forceinline__ float block_sum256(float v, float* tmp) {
    #pragma unroll
    for (int off = 32; off; off >>= 1) v += __shfl_down(v, off, 64);
    const int lane = threadIdx.x & 63, w = threadIdx.x >> 6;
    __syncthreads();
    if (lane == 0) tmp[w] = v;
    __syncthreads();
    return tmp[0] + tmp[1] + tmp[2] + tmp[3];
}

__global__ __launch_bounds__(256) void ln_kernel(const float* __restrict__ x,
    const unsigned short* __restrict__ g, const unsigned short* __restrict__ bb,
    unsigned short* __restrict__ y)
{
    __shared__ float tmp[4];
    const int row = blockIdx.x;
    const int tid = threadIdx.x;
    const float* xr = x + (size_t)row * 1024;
    float4 xv = *(const float4*)(xr + tid * 4);
    float s = (xv.x + xv.y) + (xv.z + xv.w);
    float mean = block_sum256(s, tmp) * (1.0f / 1024.0f);
    float dx = xv.x - mean, dy = xv.y - mean, dz = xv.z - mean, dw = xv.w - mean;
    float ss = dx * dx + dy * dy + dz * dz + dw * dw;
    float var = block_sum256(ss, tmp) * (1.0f / 1024.0f);
    float rstd = rsqrtf(var + 1e-5f);
    const int d = tid * 4;
    ushort4 gv = *(const ushort4*)(g + d);
    ushort4 bv = *(const ushort4*)(bb + d);
    ushort4 o;
    o.x = f2b(dx * rstd * b2f(gv.x) + b2f(bv.x));
    o.y = f2b(dy * rstd * b2f(gv.y) + b2f(bv.y));
    o.z = f2b(dz * rstd * b2f(gv.z) + b2f(bv.z));
    o.w = f2b(dw * rstd * b2f(gv.w) + b2f(bv.w));
    *(ushort4*)(y + (size_t)row * 1024 + d) = o;
}

// ---------- transpose (fp32 or bf16 in) -> bf16 out: in[eoff..][R][C] -> out[C][R] ----------
__global__ __launch_bounds__(256) void transpose_kernel(const void* __restrict__ inp, size_t eoff,
    unsigned short* __restrict__ out, int R, int C, const int* __restrict__ flags)
{
    __shared__ unsigned short T[64][72];
    const int tx = threadIdx.x & 63, ty = threadIdx.x >> 6;
    const int r0 = blockIdx.y << 6, c0 = blockIdx.x << 6;
    if (flags[0]) {
        const float* in = (const float*)inp + eoff;
        #pragma unroll
        for (int j = 0; j < 16; j++) {
            int r = ty * 16 + j;
            T[r][tx] = f2b(in[(size_t)(r0 + r) * C + c0 + tx]);
        }
    } else {
        const unsigned short* in = (const unsigned short*)inp + eoff;
        #pragma unroll
        for (int j = 0; j < 16; j++) {
            int r = ty * 16 + j;
            T[r][tx] = in[(size_t)(r0 + r) * C + c0 + tx];
        }
    }
    __syncthreads();
    #pragma unroll
    for (int j = 0; j < 16; j++) {
        int c = ty * 16 + j;
        out[(size_t)(c0 + c) * R + r0 + tx] = T[tx][c];
    }
}

// ---------- MFMA GEMM: C[M,N] = A[M,K](bf16) @ Bt[N,K](bf16)^T + bias(bf16) ----------
// BN = 128 fixed. BM in {64,128}; WC = wave-cols (WR*WC=4);
// ACT: 1 = exact GELU; OUTB: 0 fp32 out, 1 bf16 out, 2 dynamic (flags[0] ? fp32 : bf16);
// RES: add fp32 residual. SWZ: XCD-chunked block swizzle for large-N (requires
// nwg%8==0 and gridDim.y%8==0) — keeps an 8-m-tile A-group L2-resident per XCD.
template<int BM, int WC, int ACT, int OUTB, int RES, int SWZ>
__global__ __launch_bounds__(256) void gemm_kernel(
    const unsigned short* __restrict__ A,
    const unsigned short* __restrict__ Bt,
    const unsigned short* __restrict__ bias,
    const float* __restrict__ res,
    float* __restrict__ outF,
    unsigned short* __restrict__ outB,
    int N, int K, const int* __restrict__ flags)
{
    constexpr int WR = 4 / WC;
    constexpr int MT = BM / (WR * 16);
    constexpr int NT = 128 / (WC * 16);
    constexpr int CA = BM / 64;           // A 16B-chunks per thread
    __shared__ __align__(16) unsigned short As[BM * 32];
    __shared__ __align__(16) unsigned short Bs[128 * 32];

    const int tid = threadIdx.x;
    const int lane = tid & 63;
    const int w = tid >> 6;
    const int wr = (WR == 1) ? 0 : (w >> 1);
    const int wc = (WC == 2) ? (w & 1) : w;

    int bm, bn;
    if (SWZ) {
        // linear hw id -> (xcd, idx); give each XCD a contiguous slice of an
        // (mg, n, mi) enumeration: groups of 8 m-tiles iterate innermost so the
        // 8x256KB A-group stays L2-resident while B streams once per group.
        const int nb = gridDim.x;
        const int nwg = nb * gridDim.y;
        const int bid = blockIdx.y * nb + blockIdx.x;
        const int idx = (bid >> 3) + (bid & 7) * (nwg >> 3);
        const int grp = nb << 3;
        const int mg = idx / grp;
        const int rem = idx - mg * grp;
        bn = rem >> 3;
        bm = mg * 8 + (rem & 7);
    } else {
        bm = blockIdx.y; bn = blockIdx.x;
    }
    const int m0 = bm * BM;
    const int n0 = bn * 128;
    const int q = lane >> 4;
    const int l15 = lane & 15;
    int of32 = 0;
    if (OUTB == 2) of32 = flags[0];

    f32x4 acc[MT][NT];
    #pragma unroll
    for (int i = 0; i < MT; i++)
        #pragma unroll
        for (int j = 0; j < NT; j++)
            acc[i][j] = (f32x4){0.f, 0.f, 0.f, 0.f};

    for (int kt = 0; kt < K; kt += 32) {
        __syncthreads();                       // previous tile's ds_reads done
        #pragma unroll
        for (int i = 0; i < CA; i++) {
            int c = tid + i * 256;
            int r = c >> 2, ko = (c & 3) * 8;
            GLD16(A + (size_t)(m0 + r) * K + kt + ko, As + c * 8);
        }
        #pragma unroll
        for (int i = 0; i < 2; i++) {
            int c = tid + i * 256;
            int r = c >> 2, ko = (c & 3) * 8;
            GLD16(Bt + (size_t)(n0 + r) * K + kt + ko, Bs + c * 8);
        }
        asm volatile("s_waitcnt vmcnt(0)" ::: "memory");
        __syncthreads();

        short8 af[MT], bfr[NT];
        #pragma unroll
        for (int t = 0; t < MT; t++)
            af[t] = *(const short8*)(As + (wr * 64 + t * 16 + l15) * 32 + q * 8);
        #pragma unroll
        for (int t = 0; t < NT; t++)
            bfr[t] = *(const short8*)(Bs + (wc * (NT * 16) + t * 16 + l15) * 32 + q * 8);
        #pragma unroll
        for (int mt = 0; mt < MT; mt++)
            #pragma unroll
            for (int nt = 0; nt < NT; nt++)
                acc[mt][nt] = __builtin_amdgcn_mfma_f32_16x16x32_bf16(af[mt], bfr[nt], acc[mt][nt], 0, 0, 0);
    }

    // epilogue: D layout col = lane&15, row = (lane>>4)*4 + reg
    #pragma unroll
    for (int mt = 0; mt < MT; mt++) {
        int r0 = m0 + wr * 64 + mt * 16 + q * 4;
        #pragma unroll
        for (int nt = 0; nt < NT; nt++) {
            int c = n0 + wc * (NT * 16) + nt * 16 + l15;
            float bv = b2f(bias[c]);
            #pragma unroll
            for (int i = 0; i < 4; i++) {
                int r = r0 + i;
                float v = acc[mt][nt][i] + bv;
                if (RES) v += res[(size_t)r * N + c];
                if (ACT) v = 0.5f * v * (1.0f + erff(v * 0.70710678118654752f));
                if (OUTB == 1)      outB[(size_t)r * N + c] = f2b(v);
                else if (OUTB == 2) {
                    if (of32) outF[(size_t)r * N + c] = v;
                    else      outB[(size_t)r * N + c] = f2b(v);
                } else              outF[(size_t)r * N + c] = v;
            }
        }
    }
}

// ---------- attention: single-pass online softmax, fp32, ~16 KB LDS ----------
// qkv: [2048][3072] fp32 (q|k|v per row). out: [2048][1024] bf16.
__global__ __launch_bounds__(256) void attn_kernel(const float* __restrict__ qkv,
                                                   unsigned short* __restrict__ out)
{
    const int qt = blockIdx.x;           // 0..63 (16 q-rows each)
    const int bh = blockIdx.y;           // 0..31
    const int b = bh >> 4, h = bh & 15;
    const int q0 = qt << 4;
    __shared__ float Qs[16][76];
    __shared__ float Ks[16][76];
    __shared__ float Vs[16][76];
    __shared__ float Pt[16][20];
    __shared__ float Sc[16];
    __shared__ float Sum[16];
    const int tid = threadIdx.x;
    const int dd = tid & 63, r4 = tid >> 6;
    const int qi = tid >> 4, kk = tid & 15;
    const size_t base = (size_t)b * 1024 * 3072 + (size_t)h * 64;
    const int kend = q0 + 16;

    #pragma unroll
    for (int i = 0; i < 4; i++) {
        int r = r4 * 4 + i;
        Qs[r][dd] = qkv[base + (size_t)(q0 + r) * 3072 + dd] * 0.125f;  // 1/sqrt(64)
    }
    __syncthreads();
    // hoist this thread's Q row into registers (halves LDS traffic in the dot)
    float4 qreg[16];
    #pragma unroll
    for (int d4 = 0; d4 < 16; d4++) qreg[d4] = *(const float4*)&Qs[qi][d4 * 4];

    float m = -3.0e38f, sum = 0.f;
    float a0 = 0.f, a1 = 0.f, a2 = 0.f, a3 = 0.f;
    for (int kb = 0; kb < kend; kb += 16) {
        __syncthreads();                 // prev iteration's Pt/Vs/Sc readers done
        #pragma unroll
        for (int i = 0; i < 4; i++) {
            int r = r4 * 4 + i;
            Ks[r][dd] = qkv[base + 1024 + (size_t)(kb + r) * 3072 + dd];
            Vs[r][dd] = qkv[base + 2048 + (size_t)(kb + r) * 3072 + dd];
        }
        __syncthreads();
        float s = 0.f;
        #pragma unroll
        for (int d4 = 0; d4 < 16; d4++) {
            float4 qv = qreg[d4];
            float4 kv = *(const float4*)&Ks[kk][d4 * 4];
            s += qv.x * kv.x + qv.y * kv.y + qv.z * kv.z + qv.w * kv.w;
        }
        const int kg = kb + kk;
        const bool valid = (kg <= q0 + qi);
        s = valid ? s : -3.0e38f;
        float tm = s;
        #pragma unroll
        for (int off = 8; off; off >>= 1) tm = fmaxf(tm, __shfl_xor(tm, off, 16));
        float mnew = fmaxf(m, tm);
        float scale = __expf(m - mnew);      // 0 on first iteration (m = -inf)
        float e = valid ? __expf(s - mnew) : 0.f;
        float es = e;
        #pragma unroll
        for (int off = 8; off; off >>= 1) es += __shfl_xor(es, off, 16);
        sum = sum * scale + es;
        m = mnew;
        Pt[qi][kk] = e;
        if (kk == 0) Sc[qi] = scale;
        __syncthreads();
        const float s0 = Sc[r4 * 4 + 0], s1 = Sc[r4 * 4 + 1];
        const float s2 = Sc[r4 * 4 + 2], s3 = Sc[r4 * 4 + 3];
        a0 *= s0; a1 *= s1; a2 *= s2; a3 *= s3;
        #pragma unroll
        for (int j = 0; j < 16; j++) {
            float v = Vs[j][dd];
            a0 += Pt[r4 * 4 + 0][j] * v;
            a1 += Pt[r4 * 4 + 1][j] * v;
            a2 += Pt[r4 * 4 + 2][j] * v;
            a3 += Pt[r4 * 4 + 3][j] * v;
        }
    }
    if (kk == 0) Sum[qi] = sum;
    __syncthreads();
    const float r0 = 1.0f / Sum[r4 * 4 + 0];
    const float r1 = 1.0f / Sum[r4 * 4 + 1];
    const float r2 = 1.0f / Sum[r4 * 4 + 2];
    const float r3 = 1.0f / Sum[r4 * 4 + 3];
    const size_t ob = ((size_t)b * 1024 + q0) * 1024 + (size_t)h * 64 + dd;
    out[ob + (size_t)(r4 * 4 + 0) * 1024] = f2b(a0 * r0);
    out[ob + (size_t)(r4 * 4 + 1) * 1024] = f2b(a1 * r1);
    out[ob + (size_t)(r4 * 4 + 2) * 1024] = f2b(a2 * r2);
    out[ob + (size_t)(r4 * 4 + 3) * 1024] = f2b(a3 * r3);
}

// ---------- host ----------
extern "C" void kernel_launch(void* const* d_in, const int* in_sizes, int n_in,
                              void* d_out, int out_size, void* d_ws, size_t ws_size,
                              hipStream_t stream)
{
    const int D = 1024, F = 4096, V = 32000;
    const void* x    = d_in[0];
    const void* tok  = d_in[1];
    const void* pos  = d_in[2];
    const void* Wq   = d_in[3];
    const void* bq   = d_in[4];
    const void* Wk   = d_in[5];
    const void* bk   = d_in[6];
    const void* Wv   = d_in[7];
    const void* bv   = d_in[8];
    const void* Wo   = d_in[9];
    const void* bo   = d_in[10];
    const void* ln1g = d_in[11];
    const void* ln1b = d_in[12];
    const void* ln2g = d_in[13];
    const void* ln2b = d_in[14];
    const void* W1   = d_in[15];
    const void* b1   = d_in[16];
    const void* W2   = d_in[17];
    const void* b2   = d_in[18];
    const void* lnfg = d_in[19];
    const void* lnfb = d_in[20];
    const void* WoutW= d_in[21];
    const void* bout = d_in[22];

    char* ws = (char*)d_ws;
    float* h            = (float*)(ws);                       //  8,388,608 B
    float* qkv          = (float*)(ws + 8388608);             // 25,165,824 B
    unsigned short* xb  = (unsigned short*)(ws + 33554432);   //  4,194,304 B
    unsigned short* gb  = (unsigned short*)(ws + 37748736);   // 16,777,216 B
    unsigned short* wT  = (unsigned short*)(ws + 54525952);   // 65,536,000 B
    unsigned short* sb  = (unsigned short*)(ws + 120061952);  //    147,968 B
    int* flags          = (int*)(ws + 120209920);             //          8 B

    detect_kernel<<<dim3(1), dim3(256), 0, stream>>>(x, tok, flags);

    P13 ps;
    ps.p[0] = bq;  ps.p[1] = bk;  ps.p[2] = bv;  ps.p[3] = bo;
    ps.p[4] = ln1g; ps.p[5] = ln1b; ps.p[6] = ln2g; ps.p[7] = ln2b;
    ps.p[8] = b1;  ps.p[9] = b2;  ps.p[10] = lnfg; ps.p[11] = lnfb; ps.p[12] = bout;
    cvt_kernel<<<dim3(125, 13), dim3(256), 0, stream>>>(ps, sb, flags);

    embed_kernel<<<dim3(2048), dim3(256), 0, stream>>>(x, tok, pos, h, flags);

    for (int l = 0; l < 3; l++) {
        size_t oD2 = (size_t)l * D * D;
        size_t oDF = (size_t)l * D * F;
        // --- attention block ---
        ln_kernel<<<dim3(2048), dim3(256), 0, stream>>>(h, sb + 12288 + l * D, sb + 15360 + l * D, xb);
        transpose_kernel<<<dim3(16, 16), dim3(256), 0, stream>>>(Wq, oD2, wT,                   D, D, flags);
        transpose_kernel<<<dim3(16, 16), dim3(256), 0, stream>>>(Wk, oD2, wT + 1024 * 1024,     D, D, flags);
        transpose_kernel<<<dim3(16, 16), dim3(256), 0, stream>>>(Wv, oD2, wT + 2 * 1024 * 1024, D, D, flags);
        gemm_kernel<128, 2, 0, 0, 0, 0><<<dim3(24, 16), dim3(256), 0, stream>>>(
            xb, wT, sb + l * 3072, nullptr, qkv, nullptr, 3072, 1024, nullptr);
        attn_kernel<<<dim3(64, 32), dim3(256), 0, stream>>>(qkv, xb);
        transpose_kernel<<<dim3(16, 16), dim3(256), 0, stream>>>(Wo, oD2, wT, D, D, flags);
        gemm_kernel<64, 4, 0, 0, 1, 0><<<dim3(8, 32), dim3(256), 0, stream>>>(
            xb, wT, sb + 9216 + l * D, h, h, nullptr, 1024, 1024, nullptr);
        // --- FFN block ---
        ln_kernel<<<dim3(2048), dim3(256), 0, stream>>>(h, sb + 18432 + l * D, sb + 21504 + l * D, xb);
        transpose_kernel<<<dim3(64, 16), dim3(256), 0, stream>>>(W1, oDF, wT, D, F, flags);
        gemm_kernel<128, 2, 1, 1, 0, 0><<<dim3(32, 16), dim3(256), 0, stream>>>(
            xb, wT, sb + 24576 + l * F, nullptr, nullptr, gb, 4096, 1024, nullptr);
        transpose_kernel<<<dim3(16, 64), dim3(256), 0, stream>>>(W2, oDF, wT, F, D, flags);
        gemm_kernel<64, 4, 0, 0, 1, 0><<<dim3(8, 32), dim3(256), 0, stream>>>(
            gb, wT, sb + 36864 + l * D, h, h, nullptr, 1024, 4096, nullptr);
    }

    ln_kernel<<<dim3(2048), dim3(256), 0, stream>>>(h, sb + 39936, sb + 40960, xb);
    transpose_kernel<<<dim3(500, 16), dim3(256), 0, stream>>>(WoutW, 0, wT, D, V, flags);
    gemm_kernel<128, 2, 0, 2, 0, 1><<<dim3(250, 16), dim3(256), 0, stream>>>(
        xb, wT, sb + 41984, nullptr, (float*)d_out, (unsigned short*)d_out, V, 1024, flags);
}